// Round 3
// baseline (557.945 us; speedup 1.0000x reference)
//
#include <hip/hip_runtime.h>
#include <math.h>

// Problem constants: S=512, B=256, V=100000, E=128, H=256
#define S_LEN 512
#define B_SZ  256
#define E_SZ  128
#define H_SZ  256

typedef __attribute__((ext_vector_type(8))) short bf16x8;
typedef __attribute__((ext_vector_type(4))) float f32x4;

// Pre-converted W_ih (bf16 hi/lo split), written once by prep_w_kernel.
__device__ short g_wh[H_SZ * E_SZ];   // 64 KB
__device__ short g_wl[H_SZ * E_SZ];   // 64 KB

__device__ __forceinline__ unsigned pkbf(float a, float b) {
    unsigned r; asm("v_cvt_pk_bf16_f32 %0, %1, %2" : "=v"(r) : "v"(a), "v"(b));
    return r;   // lo16 = bf16(a), hi16 = bf16(b), RNE
}
__device__ __forceinline__ float fromlo(unsigned u) {
    union { unsigned u; float f; } c; c.u = u << 16; return c.f;
}
__device__ __forceinline__ float fromhi(unsigned u) {
    union { unsigned u; float f; } c; c.u = u & 0xffff0000u; return c.f;
}
// 8 fp32 -> bf16 hi fragment + bf16 lo (residual) fragment
__device__ __forceinline__ void cvt_hilo8(float4 a, float4 b, bf16x8& hi, bf16x8& lo) {
    unsigned h0 = pkbf(a.x, a.y), h1 = pkbf(a.z, a.w);
    unsigned h2 = pkbf(b.x, b.y), h3 = pkbf(b.z, b.w);
    unsigned l0 = pkbf(a.x - fromlo(h0), a.y - fromhi(h0));
    unsigned l1 = pkbf(a.z - fromlo(h1), a.w - fromhi(h1));
    unsigned l2 = pkbf(b.x - fromlo(h2), b.y - fromhi(h2));
    unsigned l3 = pkbf(b.z - fromlo(h3), b.w - fromhi(h3));
    union { bf16x8 v; unsigned u[4]; } H, L;
    H.u[0] = h0; H.u[1] = h1; H.u[2] = h2; H.u[3] = h3;
    L.u[0] = l0; L.u[1] = l1; L.u[2] = l2; L.u[3] = l3;
    hi = H.v; lo = L.v;
}

// tanh(v) = 1 - 2/(exp(2v)+1); rcp (~1 ulp) far below bf16 state noise.
__device__ __forceinline__ float tanh_fast(float v) {
    float e = __expf(2.f * v);
    return 1.f - 2.f * __builtin_amdgcn_rcpf(e + 1.f);
}

// ---------------------------------------------------------------------------
// Kernel 0: one-time W_ih -> bf16 hi/lo conversion (was redundantly done
// per-block by all 2048 embed blocks: ~1280 VALU insts/thread).
// 16 blocks x 256 threads x 8 elements = 32768 = H*E.
// ---------------------------------------------------------------------------
__global__ void prep_w_kernel(const float* __restrict__ W_ih) {
    const int i = (blockIdx.x * 256 + threadIdx.x) * 8;
    float4 a = *(const float4*)&W_ih[i];
    float4 b = *(const float4*)&W_ih[i + 4];
    bf16x8 h, l;
    cvt_hilo8(a, b, h, l);
    *(bf16x8*)&g_wh[i] = h;
    *(bf16x8*)&g_wl[i] = l;
}

// ---------------------------------------------------------------------------
// Kernel 1 (v3): embedding gather + input projection, bf16 MFMA hi/lo split
// (xp = Ah*Wh + Ah*Wl + Al*Wh, fp32-level accuracy — absmax-identical to
// fp32 in R2). No LDS, no syncthreads: B-fragments loaded directly from
// global emb at the fragment offset (mapping verified by R2's staged path),
// converted in-register with cvt_pk. W fragments from prepped globals.
// Block: 256 threads = 4 waves; wave owns 64 h (4 m-tiles) x 64 rows (4 nt).
// ---------------------------------------------------------------------------
__global__ __launch_bounds__(256, 2) void embed_proj_mfma(
    const int*   __restrict__ X,
    const float* __restrict__ emb,
    const float* __restrict__ b_ih,
    const float* __restrict__ b_hh,
    float*       __restrict__ xproj)
{
    const int tid  = threadIdx.x;
    const int wave = tid >> 6;
    const int lane = tid & 63;
    const int bl   = lane & 15;
    const int quad = lane >> 4;
    const size_t row0 = (size_t)blockIdx.x * 64;

    // token index for each of this lane's B columns (row = nt*16 + bl)
    int tok[4];
#pragma unroll
    for (int nt = 0; nt < 4; ++nt) tok[nt] = X[row0 + nt * 16 + bl];

    // A-operand fragments: lane holds A[m = wave*64+mt*16+bl][k = kk*32+quad*8+j]
    bf16x8 wh[4][4], wl[4][4];
#pragma unroll
    for (int mt = 0; mt < 4; ++mt) {
        const int off0 = (wave * 64 + mt * 16 + bl) * E_SZ + quad * 8;
#pragma unroll
        for (int kk = 0; kk < 4; ++kk) {
            wh[mt][kk] = *(const bf16x8*)&g_wh[off0 + kk * 32];
            wl[mt][kk] = *(const bf16x8*)&g_wl[off0 + kk * 32];
        }
    }

    f32x4 bias[4];
#pragma unroll
    for (int mt = 0; mt < 4; ++mt) {
        const int hb = wave * 64 + mt * 16 + quad * 4;
        float4 bi = *(const float4*)&b_ih[hb];
        float4 bh = *(const float4*)&b_hh[hb];
        bias[mt][0] = bi.x + bh.x; bias[mt][1] = bi.y + bh.y;
        bias[mt][2] = bi.z + bh.z; bias[mt][3] = bi.w + bh.w;
    }

#pragma unroll
    for (int nt = 0; nt < 4; ++nt) {
        // B-fragments direct from global: element emb[tok][kk*32+quad*8+j]
        const float* ep = emb + (size_t)tok[nt] * E_SZ + quad * 8;
        bf16x8 bh8[4], bl8[4];
#pragma unroll
        for (int kk = 0; kk < 4; ++kk) {
            float4 a = *(const float4*)(ep + kk * 32);
            float4 b = *(const float4*)(ep + kk * 32 + 4);
            cvt_hilo8(a, b, bh8[kk], bl8[kk]);
        }

        f32x4 acc[4];
#pragma unroll
        for (int mt = 0; mt < 4; ++mt) acc[mt] = (f32x4){0.f, 0.f, 0.f, 0.f};

#pragma unroll
        for (int kk = 0; kk < 4; ++kk)
#pragma unroll
            for (int mt = 0; mt < 4; ++mt) {
                f32x4 a = acc[mt];
                a = __builtin_amdgcn_mfma_f32_16x16x32_bf16(wh[mt][kk], bh8[kk], a, 0, 0, 0);
                a = __builtin_amdgcn_mfma_f32_16x16x32_bf16(wh[mt][kk], bl8[kk], a, 0, 0, 0);
                a = __builtin_amdgcn_mfma_f32_16x16x32_bf16(wl[mt][kk], bh8[kk], a, 0, 0, 0);
                acc[mt] = a;
            }

        // D layout: col = bl (row of tile), rows h = quad*4 + r
#pragma unroll
        for (int mt = 0; mt < 4; ++mt) {
            f32x4 o = acc[mt];
            o[0] += bias[mt][0]; o[1] += bias[mt][1];
            o[2] += bias[mt][2]; o[3] += bias[mt][3];
            *(f32x4*)&xproj[(row0 + nt * 16 + bl) * H_SZ + wave * 64 + mt * 16 + quad * 4] = o;
        }
    }
}

// ---------------------------------------------------------------------------
// Kernel 2 (v4): MFMA recurrent scan + log_softmax.
//  Change vs v3: 4 waves instead of 8 (wave owns 4 m-tiles = 64 h).
//  The step is LDS-pipe-gated: every wave redundantly reads the full 8KB
//  state as B-fragments, so per-step LDS time scales with wave count
//  (8 waves: 64 b128 reads ~770cyc; 4 waves: 32 reads ~385cyc) while
//  MFMA-issue/SIMD and trans/SIMD stay constant.
// ---------------------------------------------------------------------------
__global__ __launch_bounds__(256, 1) void rnn_scan_kernel(
    const float* __restrict__ xproj,
    const float* __restrict__ W_hh,
    float*       __restrict__ out)
{
    const int tid  = threadIdx.x;
    const int wave = tid >> 6;      // 0..3
    const int lane = tid & 63;
    const int bl   = lane & 15;     // batch within block
    const int quad = lane >> 4;     // 0..3
    const int B0   = blockIdx.x * 16;

    __shared__ short HB[2][4096];   // 2 x 8KB state buffers
    __shared__ float sred[4][16];

    // ---- A-operand: W_hh fragments, constant through the scan ----
    // lane holds A[m = wave*64 + mt*16 + bl][k = kk*32 + quad*8 + j]
    bf16x8 wfrag[4][8];
#pragma unroll
    for (int mt = 0; mt < 4; ++mt) {
        const int h = wave * 64 + mt * 16 + bl;
#pragma unroll
        for (int kk = 0; kk < 8; ++kk) {
            const float* wp = W_hh + (size_t)h * H_SZ + kk * 32 + quad * 8;
            float4 a = *(const float4*)wp;
            float4 b = *(const float4*)(wp + 4);
            union { bf16x8 v; unsigned u[4]; } F;
            F.u[0] = pkbf(a.x, a.y); F.u[1] = pkbf(a.z, a.w);
            F.u[2] = pkbf(b.x, b.y); F.u[3] = pkbf(b.z, b.w);
            wfrag[mt][kk] = F.v;
        }
    }

    short* const hb0 = HB[0];
    short* const hb1 = HB[1];
    ((int4*)hb0)[tid]       = make_int4(0, 0, 0, 0);   // zero initial state
    ((int4*)hb0)[tid + 256] = make_int4(0, 0, 0, 0);

    // read base: lane's 8 B-fragments at kk*1024B + lane*16B (conflict-free)
    const short* rd0 = hb0 + lane * 8;
    const short* rd1 = hb1 + lane * 8;

    // write slot for (h = wave*64 + mt*16 + quad*4 + r, batch bl):
    // shorts offset (h>>5)*512 + ((h>>3)&3)*128 + bl*8 + (h&7)
    //   = wave*1024 + (quad>>1)*128 + bl*8 + (quad&1)*4  + mt*256
    const int wbase = wave * 1024 + (quad >> 1) * 128 + bl * 8 + (quad & 1) * 4;
    short* const w0 = hb0 + wbase;
    short* const w1 = hb1 + wbase;

    const size_t stp = (size_t)B_SZ * H_SZ;
    const float* xpb = xproj + (size_t)(B0 + bl) * H_SZ + wave * 64 + quad * 4;

    // distance-2 prefetch register sets (A: even steps, B: odd steps)
    f32x4 xA0 = *(const f32x4*)(xpb);
    f32x4 xA1 = *(const f32x4*)(xpb + 16);
    f32x4 xA2 = *(const f32x4*)(xpb + 32);
    f32x4 xA3 = *(const f32x4*)(xpb + 48);
    f32x4 xB0 = *(const f32x4*)(xpb + stp);
    f32x4 xB1 = *(const f32x4*)(xpb + stp + 16);
    f32x4 xB2 = *(const f32x4*)(xpb + stp + 32);
    f32x4 xB3 = *(const f32x4*)(xpb + stp + 48);

    __syncthreads();

    auto do_step = [&](const short* rd, short* wr,
                       f32x4& x0, f32x4& x1, f32x4& x2, f32x4& x3,
                       const float* pf) {
        bf16x8 bf[8];
#pragma unroll
        for (int kk = 0; kk < 8; ++kk)
            bf[kk] = *(const bf16x8*)(rd + kk * 512);

        // 8 independent MFMA chains of 4 (4 m-tiles x 2 k-halves)
        f32x4 ca0 = {0.f,0.f,0.f,0.f}, ca1 = {0.f,0.f,0.f,0.f};
        f32x4 ca2 = {0.f,0.f,0.f,0.f}, ca3 = {0.f,0.f,0.f,0.f};
        f32x4 cb0 = {0.f,0.f,0.f,0.f}, cb1 = {0.f,0.f,0.f,0.f};
        f32x4 cb2 = {0.f,0.f,0.f,0.f}, cb3 = {0.f,0.f,0.f,0.f};
#pragma unroll
        for (int kk = 0; kk < 4; ++kk) {
            ca0 = __builtin_amdgcn_mfma_f32_16x16x32_bf16(wfrag[0][kk],   bf[kk],   ca0, 0, 0, 0);
            ca1 = __builtin_amdgcn_mfma_f32_16x16x32_bf16(wfrag[1][kk],   bf[kk],   ca1, 0, 0, 0);
            ca2 = __builtin_amdgcn_mfma_f32_16x16x32_bf16(wfrag[2][kk],   bf[kk],   ca2, 0, 0, 0);
            ca3 = __builtin_amdgcn_mfma_f32_16x16x32_bf16(wfrag[3][kk],   bf[kk],   ca3, 0, 0, 0);
            cb0 = __builtin_amdgcn_mfma_f32_16x16x32_bf16(wfrag[0][kk+4], bf[kk+4], cb0, 0, 0, 0);
            cb1 = __builtin_amdgcn_mfma_f32_16x16x32_bf16(wfrag[1][kk+4], bf[kk+4], cb1, 0, 0, 0);
            cb2 = __builtin_amdgcn_mfma_f32_16x16x32_bf16(wfrag[2][kk+4], bf[kk+4], cb2, 0, 0, 0);
            cb3 = __builtin_amdgcn_mfma_f32_16x16x32_bf16(wfrag[3][kk+4], bf[kk+4], cb3, 0, 0, 0);
        }
        const f32x4 d0 = ca0 + cb0, d1 = ca1 + cb1;
        const f32x4 d2 = ca2 + cb2, d3 = ca3 + cb3;

        // epilogue per m-tile: v = D + xp, tanh, pack, store next state
#define EPI(dd, xx, OFF) { \
        float t0 = tanh_fast(dd[0] + xx[0]); \
        float t1 = tanh_fast(dd[1] + xx[1]); \
        float t2 = tanh_fast(dd[2] + xx[2]); \
        float t3 = tanh_fast(dd[3] + xx[3]); \
        unsigned pa = pkbf(t0, t1), pb = pkbf(t2, t3); \
        *(uint2*)(wr + (OFF)) = make_uint2(pa, pb); }
        EPI(d0, x0, 0)
        EPI(d1, x1, 256)
        EPI(d2, x2, 512)
        EPI(d3, x3, 768)
#undef EPI

        // issue prefetch for step s+2 into the registers just consumed
        x0 = *(const f32x4*)pf;
        x1 = *(const f32x4*)(pf + 16);
        x2 = *(const f32x4*)(pf + 32);
        x3 = *(const f32x4*)(pf + 48);

        // own LDS ops done -> barrier. No vmcnt drain: prefetch stays in flight.
        asm volatile("s_waitcnt lgkmcnt(0)" ::: "memory");
        __builtin_amdgcn_sched_barrier(0);
        __builtin_amdgcn_s_barrier();
    };

    const float* pfA = xpb + 2 * stp;
    const float* pfB = xpb + 3 * stp;
    for (int s = 0; s < 510; s += 2) {
        do_step(rd0, w1, xA0, xA1, xA2, xA3, pfA);   // even step s
        do_step(rd1, w0, xB0, xB1, xB2, xB3, pfB);   // odd step s+1
        pfA += 2 * stp; pfB += 2 * stp;
        if (pfA > xpb + 511 * stp) pfA = xpb;        // clamp (dummy in-bounds)
        if (pfB > xpb + 511 * stp) pfB = xpb;
    }
    do_step(rd0, w1, xA0, xA1, xA2, xA3, xpb);       // step 510

    // step 511 peeled: read buf1, keep fp32 tanh values for log_softmax
    float vf[4][4];
    {
        bf16x8 bf[8];
#pragma unroll
        for (int kk = 0; kk < 8; ++kk)
            bf[kk] = *(const bf16x8*)(rd1 + kk * 512);
        f32x4 ca0 = {0.f,0.f,0.f,0.f}, ca1 = {0.f,0.f,0.f,0.f};
        f32x4 ca2 = {0.f,0.f,0.f,0.f}, ca3 = {0.f,0.f,0.f,0.f};
        f32x4 cb0 = {0.f,0.f,0.f,0.f}, cb1 = {0.f,0.f,0.f,0.f};
        f32x4 cb2 = {0.f,0.f,0.f,0.f}, cb3 = {0.f,0.f,0.f,0.f};
#pragma unroll
        for (int kk = 0; kk < 4; ++kk) {
            ca0 = __builtin_amdgcn_mfma_f32_16x16x32_bf16(wfrag[0][kk],   bf[kk],   ca0, 0, 0, 0);
            ca1 = __builtin_amdgcn_mfma_f32_16x16x32_bf16(wfrag[1][kk],   bf[kk],   ca1, 0, 0, 0);
            ca2 = __builtin_amdgcn_mfma_f32_16x16x32_bf16(wfrag[2][kk],   bf[kk],   ca2, 0, 0, 0);
            ca3 = __builtin_amdgcn_mfma_f32_16x16x32_bf16(wfrag[3][kk],   bf[kk],   ca3, 0, 0, 0);
            cb0 = __builtin_amdgcn_mfma_f32_16x16x32_bf16(wfrag[0][kk+4], bf[kk+4], cb0, 0, 0, 0);
            cb1 = __builtin_amdgcn_mfma_f32_16x16x32_bf16(wfrag[1][kk+4], bf[kk+4], cb1, 0, 0, 0);
            cb2 = __builtin_amdgcn_mfma_f32_16x16x32_bf16(wfrag[2][kk+4], bf[kk+4], cb2, 0, 0, 0);
            cb3 = __builtin_amdgcn_mfma_f32_16x16x32_bf16(wfrag[3][kk+4], bf[kk+4], cb3, 0, 0, 0);
        }
        const f32x4 d0 = ca0 + cb0, d1 = ca1 + cb1;
        const f32x4 d2 = ca2 + cb2, d3 = ca3 + cb3;
#pragma unroll
        for (int r = 0; r < 4; ++r) {
            vf[0][r] = tanh_fast(d0[r] + xB0[r]);
            vf[1][r] = tanh_fast(d1[r] + xB1[r]);
            vf[2][r] = tanh_fast(d2[r] + xB2[r]);
            vf[3][r] = tanh_fast(d3[r] + xB3[r]);
        }
    }

    // ---- log_softmax over h=256 for each batch row bl ----
    float m = -1e30f;
#pragma unroll
    for (int mt = 0; mt < 4; ++mt)
#pragma unroll
        for (int r = 0; r < 4; ++r) m = fmaxf(m, vf[mt][r]);
    m = fmaxf(m, __shfl_xor(m, 16));
    m = fmaxf(m, __shfl_xor(m, 32));
    if (lane < 16) sred[wave][bl] = m;
    __syncthreads();
    const float mall = fmaxf(fmaxf(sred[0][bl], sred[1][bl]),
                             fmaxf(sred[2][bl], sred[3][bl]));
    __syncthreads();

    float ss = 0.f;
#pragma unroll
    for (int mt = 0; mt < 4; ++mt)
#pragma unroll
        for (int r = 0; r < 4; ++r) ss += __expf(vf[mt][r] - mall);
    ss += __shfl_xor(ss, 16);
    ss += __shfl_xor(ss, 32);
    if (lane < 16) sred[wave][bl] = ss;
    __syncthreads();
    const float tot = sred[0][bl] + sred[1][bl] + sred[2][bl] + sred[3][bl];
    const float lse = mall + __logf(tot);

    float* op = out + (size_t)(B0 + bl) * H_SZ + wave * 64 + quad * 4;
#pragma unroll
    for (int mt = 0; mt < 4; ++mt) {
        f32x4 o;
#pragma unroll
        for (int r = 0; r < 4; ++r) o[r] = vf[mt][r] - lse;
        *(f32x4*)(op + mt * 16) = o;
    }
}

// ---------------------------------------------------------------------------
extern "C" void kernel_launch(void* const* d_in, const int* in_sizes, int n_in,
                              void* d_out, int out_size, void* d_ws, size_t ws_size,
                              hipStream_t stream) {
    const int*   X    = (const int*)  d_in[0];
    const float* emb  = (const float*)d_in[1];
    const float* W_ih = (const float*)d_in[2];
    const float* W_hh = (const float*)d_in[3];
    const float* b_ih = (const float*)d_in[4];
    const float* b_hh = (const float*)d_in[5];
    float* out   = (float*)d_out;
    float* xproj = (float*)d_ws;   // S*B*H fp32 = 134.2 MB

    prep_w_kernel<<<dim3(16), 256, 0, stream>>>(W_ih);
    embed_proj_mfma<<<dim3((S_LEN * B_SZ) / 64), 256, 0, stream>>>(
        X, emb, b_ih, b_hh, xproj);
    rnn_scan_kernel<<<dim3(B_SZ / 16), 256, 0, stream>>>(xproj, W_hh, out);
}

// Round 4
// 542.791 us; speedup vs baseline: 1.0279x; 1.0279x over previous
//
#include <hip/hip_runtime.h>
#include <math.h>

// Problem constants: S=512, B=256, V=100000, E=128, H=256
#define S_LEN 512
#define B_SZ  256
#define E_SZ  128
#define H_SZ  256

typedef __attribute__((ext_vector_type(8))) short bf16x8;
typedef __attribute__((ext_vector_type(4))) float f32x4;

// Pre-converted W_ih (bf16 hi/lo split), written once by prep_w_kernel.
__device__ short g_wh[H_SZ * E_SZ];   // 64 KB
__device__ short g_wl[H_SZ * E_SZ];   // 64 KB

__device__ __forceinline__ unsigned pkbf(float a, float b) {
    unsigned r; asm("v_cvt_pk_bf16_f32 %0, %1, %2" : "=v"(r) : "v"(a), "v"(b));
    return r;   // lo16 = bf16(a), hi16 = bf16(b), RNE
}
__device__ __forceinline__ float fromlo(unsigned u) {
    union { unsigned u; float f; } c; c.u = u << 16; return c.f;
}
__device__ __forceinline__ float fromhi(unsigned u) {
    union { unsigned u; float f; } c; c.u = u & 0xffff0000u; return c.f;
}
// 8 fp32 -> bf16 hi fragment + bf16 lo (residual) fragment
__device__ __forceinline__ void cvt_hilo8(float4 a, float4 b, bf16x8& hi, bf16x8& lo) {
    unsigned h0 = pkbf(a.x, a.y), h1 = pkbf(a.z, a.w);
    unsigned h2 = pkbf(b.x, b.y), h3 = pkbf(b.z, b.w);
    unsigned l0 = pkbf(a.x - fromlo(h0), a.y - fromhi(h0));
    unsigned l1 = pkbf(a.z - fromlo(h1), a.w - fromhi(h1));
    unsigned l2 = pkbf(b.x - fromlo(h2), b.y - fromhi(h2));
    unsigned l3 = pkbf(b.z - fromlo(h3), b.w - fromhi(h3));
    union { bf16x8 v; unsigned u[4]; } H, L;
    H.u[0] = h0; H.u[1] = h1; H.u[2] = h2; H.u[3] = h3;
    L.u[0] = l0; L.u[1] = l1; L.u[2] = l2; L.u[3] = l3;
    hi = H.v; lo = L.v;
}

// tanh(v) = 1 - 2/(exp2(C*v)+1), C = 2*log2(e). Same math path as
// __expf(2v) (which lowers to exp2(2v*log2e)) but one mul shorter.
__device__ __forceinline__ float tanhC(float v) {
    float e = __builtin_amdgcn_exp2f(v * 2.8853900818f);
    return fmaf(-2.f, __builtin_amdgcn_rcpf(e + 1.f), 1.f);
}

// ---------------------------------------------------------------------------
// Kernel 0: one-time W_ih -> bf16 hi/lo conversion.
// 16 blocks x 256 threads x 8 elements = 32768 = H*E.
// ---------------------------------------------------------------------------
__global__ void prep_w_kernel(const float* __restrict__ W_ih) {
    const int i = (blockIdx.x * 256 + threadIdx.x) * 8;
    float4 a = *(const float4*)&W_ih[i];
    float4 b = *(const float4*)&W_ih[i + 4];
    bf16x8 h, l;
    cvt_hilo8(a, b, h, l);
    *(bf16x8*)&g_wh[i] = h;
    *(bf16x8*)&g_wl[i] = l;
}

// ---------------------------------------------------------------------------
// Kernel 1 (v4): hybrid of R2 (coalesced LDS staging of emb) and R3
// (pre-converted W from g_wh/g_wl — no per-block redundant conversion).
// Block: 256 threads = 4 waves, 64 rows x full H=256; hi/lo split MFMA.
// ---------------------------------------------------------------------------
__global__ __launch_bounds__(256, 2) void embed_proj_mfma(
    const int*   __restrict__ X,
    const float* __restrict__ emb,
    const float* __restrict__ b_ih,
    const float* __restrict__ b_hh,
    float*       __restrict__ xproj)
{
    __shared__ int   toks[64];
    __shared__ short BtH[4][4][64][8];   // [ntile][kk][lane][j] hi, 16KB
    __shared__ short BtL[4][4][64][8];   // lo, 16KB

    const int tid  = threadIdx.x;
    const int wave = tid >> 6;           // 0..3
    const int lane = tid & 63;
    const int bl   = lane & 15;
    const int quad = lane >> 4;
    const size_t row0 = (size_t)blockIdx.x * 64;

    if (tid < 64) toks[tid] = X[row0 + tid];
    __syncthreads();

    // ---- stage emb tile (hi/lo bf16) into B-frag-linear LDS (coalesced) ----
    {
        const int r  = tid >> 2;         // 0..63 row
        const int kk = tid & 3;          // k-chunk of 32
        const float* ep = emb + (size_t)toks[r] * E_SZ + kk * 32;
#pragma unroll
        for (int q = 0; q < 4; ++q) {
            float4 a = *(const float4*)(ep + q * 8);
            float4 b = *(const float4*)(ep + q * 8 + 4);
            bf16x8 fh, fl;
            cvt_hilo8(a, b, fh, fl);
            *(bf16x8*)&BtH[r >> 4][kk][q * 16 + (r & 15)][0] = fh;
            *(bf16x8*)&BtL[r >> 4][kk][q * 16 + (r & 15)][0] = fl;
        }
    }
    __syncthreads();

    // ---- compute: 2 passes x 2 m-tiles; D[m=h][n=row] = W_ih * Emb^T ----
#pragma unroll
    for (int mp = 0; mp < 2; ++mp) {
        bf16x8 wh[2][4], wl[2][4];
#pragma unroll
        for (int i = 0; i < 2; ++i) {
            const int off0 = (wave * 64 + (mp * 2 + i) * 16 + bl) * E_SZ + quad * 8;
#pragma unroll
            for (int kk = 0; kk < 4; ++kk) {
                wh[i][kk] = *(const bf16x8*)&g_wh[off0 + kk * 32];
                wl[i][kk] = *(const bf16x8*)&g_wl[off0 + kk * 32];
            }
        }

        f32x4 acc[2][4];
#pragma unroll
        for (int i = 0; i < 2; ++i)
#pragma unroll
            for (int nt = 0; nt < 4; ++nt) acc[i][nt] = (f32x4){0.f, 0.f, 0.f, 0.f};

#pragma unroll
        for (int kk = 0; kk < 4; ++kk) {
            bf16x8 bh[4], blo[4];
#pragma unroll
            for (int nt = 0; nt < 4; ++nt) {
                bh[nt]  = *(const bf16x8*)&BtH[nt][kk][lane][0];
                blo[nt] = *(const bf16x8*)&BtL[nt][kk][lane][0];
            }
#pragma unroll
            for (int i = 0; i < 2; ++i)
#pragma unroll
                for (int nt = 0; nt < 4; ++nt) {
                    f32x4 a = acc[i][nt];
                    a = __builtin_amdgcn_mfma_f32_16x16x32_bf16(wh[i][kk], bh[nt],  a, 0, 0, 0);
                    a = __builtin_amdgcn_mfma_f32_16x16x32_bf16(wh[i][kk], blo[nt], a, 0, 0, 0);
                    a = __builtin_amdgcn_mfma_f32_16x16x32_bf16(wl[i][kk], bh[nt],  a, 0, 0, 0);
                    acc[i][nt] = a;
                }
        }

        // epilogue: bias + store. lane holds col=n (row nt*16+bl), rows h=quad*4+r
#pragma unroll
        for (int i = 0; i < 2; ++i) {
            const int hb = wave * 64 + (mp * 2 + i) * 16 + quad * 4;
            float4 bi  = *(const float4*)&b_ih[hb];
            float4 bh4 = *(const float4*)&b_hh[hb];
#pragma unroll
            for (int nt = 0; nt < 4; ++nt) {
                f32x4 o = acc[i][nt];
                o[0] += bi.x + bh4.x; o[1] += bi.y + bh4.y;
                o[2] += bi.z + bh4.z; o[3] += bi.w + bh4.w;
                *(f32x4*)&xproj[(row0 + nt * 16 + bl) * H_SZ + hb] = o;
            }
        }
    }
}

// ---------------------------------------------------------------------------
// Kernel 2 (v5): 8-wave MFMA scan (revert of R3's 4-wave regression) with
// critical-path micro-opts:
//  - first MFMA chain's C-operand initialized with xp (accumulator fragment
//    layout == xq load layout) -> the "+xp" add vanishes from the chain.
//  - 4 chains of depth 2 per m-tile (was 2 of depth 4): -~50 cyc dep latency.
//  - tanh via exp2(C*v): one mul shorter than __expf(2v), identical math.
//  - xp prefetch issued before the MFMAs.
// ---------------------------------------------------------------------------
__global__ __launch_bounds__(512) void rnn_scan_kernel(
    const float* __restrict__ xproj,
    const float* __restrict__ W_hh,
    float*       __restrict__ out)
{
    const int tid  = threadIdx.x;
    const int wave = tid >> 6;      // 0..7
    const int lane = tid & 63;
    const int bl   = lane & 15;     // batch within block
    const int quad = lane >> 4;     // 0..3
    const int B0   = blockIdx.x * 16;

    __shared__ short HB[2][8][64][8];   // 2 x 8KB state buffers
    __shared__ float sred[8][16];

    // ---- A-operand: W_hh fragments, constant through the scan ----
    // lane holds A[m = wave*32 + mt*16 + bl][k = kk*32 + quad*8 + j]
    bf16x8 wfrag[2][8];
#pragma unroll
    for (int mt = 0; mt < 2; ++mt) {
        const int h = wave * 32 + mt * 16 + bl;
#pragma unroll
        for (int kk = 0; kk < 8; ++kk) {
            const float* wp = W_hh + (size_t)h * H_SZ + kk * 32 + quad * 8;
            float4 a = *(const float4*)wp;
            float4 b = *(const float4*)(wp + 4);
            union { bf16x8 v; unsigned u[4]; } F;
            F.u[0] = pkbf(a.x, a.y); F.u[1] = pkbf(a.z, a.w);
            F.u[2] = pkbf(b.x, b.y); F.u[3] = pkbf(b.z, b.w);
            wfrag[mt][kk] = F.v;
        }
    }

    short* const hb0 = &HB[0][0][0][0];
    short* const hb1 = &HB[1][0][0][0];

    ((int4*)hb0)[tid] = make_int4(0, 0, 0, 0);   // zero initial state (8KB)

    const short* rd0 = hb0 + lane * 8;
    const short* rd1 = hb1 + lane * 8;

    // write slots: h -> shorts offset (h>>5)*512 + ((h>>3)&3)*128 + bl*8 + (h&7)
    const int wo0 = wave * 512 + (quad >> 1) * 128 + bl * 8 + (quad & 1) * 4;
    const int wo1 = wo0 + 256;
    short* w0a = hb0 + wo0; short* w0b = hb0 + wo1;
    short* w1a = hb1 + wo0; short* w1b = hb1 + wo1;

    const size_t stp = (size_t)B_SZ * H_SZ;
    const float* xpb = xproj + (size_t)(B0 + bl) * H_SZ + wave * 32 + quad * 4;

    // distance-2 prefetch register sets
    f32x4 xA0 = *(const f32x4*)(xpb);
    f32x4 xA1 = *(const f32x4*)(xpb + 16);
    f32x4 xB0 = *(const f32x4*)(xpb + stp);
    f32x4 xB1 = *(const f32x4*)(xpb + stp + 16);

    __syncthreads();

    auto do_step = [&](const short* rd, short* wa, short* wb,
                       f32x4& x0, f32x4& x1, const float* pf) {
        // B-fragments: 8 x ds_read_b128, conflict-free contiguous
        bf16x8 bf[8];
#pragma unroll
        for (int kk = 0; kk < 8; ++kk)
            bf[kk] = *(const bf16x8*)(rd + kk * 512);

        // issue xp prefetch for step s+2 early (overlaps MFMAs)
        f32x4 n0 = *(const f32x4*)pf;
        f32x4 n1 = *(const f32x4*)(pf + 16);

        // 8 chains of depth 2 (2 m-tiles x 4 k-quarters); first chain
        // carries xp as the C-init.
        f32x4 a0 = x0, a1 = x1;
        f32x4 b0 = {0.f,0.f,0.f,0.f}, b1 = {0.f,0.f,0.f,0.f};
        f32x4 c0 = {0.f,0.f,0.f,0.f}, c1 = {0.f,0.f,0.f,0.f};
        f32x4 e0 = {0.f,0.f,0.f,0.f}, e1 = {0.f,0.f,0.f,0.f};
        a0 = __builtin_amdgcn_mfma_f32_16x16x32_bf16(wfrag[0][0], bf[0], a0, 0, 0, 0);
        a1 = __builtin_amdgcn_mfma_f32_16x16x32_bf16(wfrag[1][0], bf[0], a1, 0, 0, 0);
        a0 = __builtin_amdgcn_mfma_f32_16x16x32_bf16(wfrag[0][1], bf[1], a0, 0, 0, 0);
        a1 = __builtin_amdgcn_mfma_f32_16x16x32_bf16(wfrag[1][1], bf[1], a1, 0, 0, 0);
        b0 = __builtin_amdgcn_mfma_f32_16x16x32_bf16(wfrag[0][2], bf[2], b0, 0, 0, 0);
        b1 = __builtin_amdgcn_mfma_f32_16x16x32_bf16(wfrag[1][2], bf[2], b1, 0, 0, 0);
        b0 = __builtin_amdgcn_mfma_f32_16x16x32_bf16(wfrag[0][3], bf[3], b0, 0, 0, 0);
        b1 = __builtin_amdgcn_mfma_f32_16x16x32_bf16(wfrag[1][3], bf[3], b1, 0, 0, 0);
        c0 = __builtin_amdgcn_mfma_f32_16x16x32_bf16(wfrag[0][4], bf[4], c0, 0, 0, 0);
        c1 = __builtin_amdgcn_mfma_f32_16x16x32_bf16(wfrag[1][4], bf[4], c1, 0, 0, 0);
        c0 = __builtin_amdgcn_mfma_f32_16x16x32_bf16(wfrag[0][5], bf[5], c0, 0, 0, 0);
        c1 = __builtin_amdgcn_mfma_f32_16x16x32_bf16(wfrag[1][5], bf[5], c1, 0, 0, 0);
        e0 = __builtin_amdgcn_mfma_f32_16x16x32_bf16(wfrag[0][6], bf[6], e0, 0, 0, 0);
        e1 = __builtin_amdgcn_mfma_f32_16x16x32_bf16(wfrag[1][6], bf[6], e1, 0, 0, 0);
        e0 = __builtin_amdgcn_mfma_f32_16x16x32_bf16(wfrag[0][7], bf[7], e0, 0, 0, 0);
        e1 = __builtin_amdgcn_mfma_f32_16x16x32_bf16(wfrag[1][7], bf[7], e1, 0, 0, 0);
        const f32x4 d0 = (a0 + b0) + (c0 + e0);
        const f32x4 d1 = (a1 + b1) + (c1 + e1);

        // epilogue: tanh, pack bf16, store next state
        float t0 = tanhC(d0[0]), t1 = tanhC(d0[1]);
        float t2 = tanhC(d0[2]), t3 = tanhC(d0[3]);
        float u0 = tanhC(d1[0]), u1 = tanhC(d1[1]);
        float u2 = tanhC(d1[2]), u3 = tanhC(d1[3]);
        *(uint2*)wa = make_uint2(pkbf(t0, t1), pkbf(t2, t3));
        *(uint2*)wb = make_uint2(pkbf(u0, u1), pkbf(u2, u3));

        x0 = n0; x1 = n1;

        // own LDS ops done -> barrier. No vmcnt drain: prefetch stays in flight.
        asm volatile("s_waitcnt lgkmcnt(0)" ::: "memory");
        __builtin_amdgcn_sched_barrier(0);
        __builtin_amdgcn_s_barrier();
    };

    const float* pfA = xpb + 2 * stp;
    const float* pfB = xpb + 3 * stp;
    for (int s = 0; s < 510; s += 2) {
        do_step(rd0, w1a, w1b, xA0, xA1, pfA);    // even step s
        do_step(rd1, w0a, w0b, xB0, xB1, pfB);    // odd step s+1
        pfA += 2 * stp; pfB += 2 * stp;
        if (pfA > xpb + 511 * stp) pfA = xpb;     // clamp (dummy in-bounds)
        if (pfB > xpb + 511 * stp) pfB = xpb;
    }
    do_step(rd0, w1a, w1b, xA0, xA1, xpb);        // step 510

    // step 511 peeled: read buf1, keep fp32 tanh values for log_softmax
    float vf0[4], vf1[4];
    {
        bf16x8 bf[8];
#pragma unroll
        for (int kk = 0; kk < 8; ++kk)
            bf[kk] = *(const bf16x8*)(rd1 + kk * 512);
        f32x4 a0 = xB0, a1 = xB1;
        f32x4 b0 = {0.f,0.f,0.f,0.f}, b1 = {0.f,0.f,0.f,0.f};
        f32x4 c0 = {0.f,0.f,0.f,0.f}, c1 = {0.f,0.f,0.f,0.f};
        f32x4 e0 = {0.f,0.f,0.f,0.f}, e1 = {0.f,0.f,0.f,0.f};
#pragma unroll
        for (int kk = 0; kk < 2; ++kk) {
            a0 = __builtin_amdgcn_mfma_f32_16x16x32_bf16(wfrag[0][kk],     bf[kk],     a0, 0, 0, 0);
            a1 = __builtin_amdgcn_mfma_f32_16x16x32_bf16(wfrag[1][kk],     bf[kk],     a1, 0, 0, 0);
            b0 = __builtin_amdgcn_mfma_f32_16x16x32_bf16(wfrag[0][kk + 2], bf[kk + 2], b0, 0, 0, 0);
            b1 = __builtin_amdgcn_mfma_f32_16x16x32_bf16(wfrag[1][kk + 2], bf[kk + 2], b1, 0, 0, 0);
            c0 = __builtin_amdgcn_mfma_f32_16x16x32_bf16(wfrag[0][kk + 4], bf[kk + 4], c0, 0, 0, 0);
            c1 = __builtin_amdgcn_mfma_f32_16x16x32_bf16(wfrag[1][kk + 4], bf[kk + 4], c1, 0, 0, 0);
            e0 = __builtin_amdgcn_mfma_f32_16x16x32_bf16(wfrag[0][kk + 6], bf[kk + 6], e0, 0, 0, 0);
            e1 = __builtin_amdgcn_mfma_f32_16x16x32_bf16(wfrag[1][kk + 6], bf[kk + 6], e1, 0, 0, 0);
        }
        const f32x4 d0 = (a0 + b0) + (c0 + e0);
        const f32x4 d1 = (a1 + b1) + (c1 + e1);
#pragma unroll
        for (int r = 0; r < 4; ++r) {
            vf0[r] = tanhC(d0[r]);
            vf1[r] = tanhC(d1[r]);
        }
    }

    // ---- log_softmax over h=256 for each batch row bl ----
    float m = fmaxf(fmaxf(fmaxf(vf0[0], vf0[1]), fmaxf(vf0[2], vf0[3])),
                    fmaxf(fmaxf(vf1[0], vf1[1]), fmaxf(vf1[2], vf1[3])));
    m = fmaxf(m, __shfl_xor(m, 16));
    m = fmaxf(m, __shfl_xor(m, 32));
    if (lane < 16) sred[wave][bl] = m;
    __syncthreads();
    float mall = sred[0][bl];
#pragma unroll
    for (int w = 1; w < 8; ++w) mall = fmaxf(mall, sred[w][bl]);
    __syncthreads();

    float ss = 0.f;
#pragma unroll
    for (int r = 0; r < 4; ++r)
        ss += __expf(vf0[r] - mall) + __expf(vf1[r] - mall);
    ss += __shfl_xor(ss, 16);
    ss += __shfl_xor(ss, 32);
    if (lane < 16) sred[wave][bl] = ss;
    __syncthreads();
    float tot = sred[0][bl];
#pragma unroll
    for (int w = 1; w < 8; ++w) tot += sred[w][bl];
    const float lse = mall + __logf(tot);

    f32x4 o0, o1;
#pragma unroll
    for (int r = 0; r < 4; ++r) { o0[r] = vf0[r] - lse; o1[r] = vf1[r] - lse; }
    float* op = out + (size_t)(B0 + bl) * H_SZ + wave * 32 + quad * 4;
    *(f32x4*)op        = o0;
    *(f32x4*)(op + 16) = o1;
}

// ---------------------------------------------------------------------------
extern "C" void kernel_launch(void* const* d_in, const int* in_sizes, int n_in,
                              void* d_out, int out_size, void* d_ws, size_t ws_size,
                              hipStream_t stream) {
    const int*   X    = (const int*)  d_in[0];
    const float* emb  = (const float*)d_in[1];
    const float* W_ih = (const float*)d_in[2];
    const float* W_hh = (const float*)d_in[3];
    const float* b_ih = (const float*)d_in[4];
    const float* b_hh = (const float*)d_in[5];
    float* out   = (float*)d_out;
    float* xproj = (float*)d_ws;   // S*B*H fp32 = 134.2 MB

    prep_w_kernel<<<dim3(16), 256, 0, stream>>>(W_ih);
    embed_proj_mfma<<<dim3((S_LEN * B_SZ) / 64), 256, 0, stream>>>(
        X, emb, b_ih, b_hh, xproj);
    rnn_scan_kernel<<<dim3(B_SZ / 16), 512, 0, stream>>>(xproj, W_hh, out);
}